// Round 8
// baseline (299.283 us; speedup 1.0000x reference)
//
#include <hip/hip_runtime.h>
#include <hip/hip_bf16.h>
#include <math.h>
#include <stdint.h>

typedef __bf16 bf16_t;
typedef __bf16 bf16x8 __attribute__((ext_vector_type(8)));
typedef float  f32x4  __attribute__((ext_vector_type(4)));
typedef _Float16 f16x4 __attribute__((ext_vector_type(4)));

#define L_LEN 8192
#define MODES 64
#define NCOMP 128      // 2*MODES (Re | Im)
#define M_ROWS 4096    // B * n_env * ch
#define SPLITS 8       // K-splits in stage1 (k-chunk 1024 per block)
#define NCH 16         // 64-wide sub-chunks per block (1024/64)

// async global->LDS, 16B per lane. LDS dst must be wave-uniform base + lane*16.
__device__ __forceinline__ void g2lds16(const void* g, void* l) {
  __builtin_amdgcn_global_load_lds(
      (__attribute__((address_space(1))) void*)(uintptr_t)(g),
      (__attribute__((address_space(3))) void*)(l), 16, 0, 0);
}

// ---------------------------------------------------------------------------
// prep = gen_basis (blocks [0,512)) + wmix (blocks [512,1536), 2 k per thread).
// Trig: __sincosf (native v_sin/v_cos) — bf16 output tolerates few-ulp error.
// B1t[n][l]  n<64: cos(2*pi*n*l/L)   n>=64: -sin(2*pi*(n-64)*l/L)   [128][8192]
// B1 [l][n]  same values transposed                                  [8192][128]
// W[e][i][o][k] (cplx f32) = lam[k]*cw[i][o][k] + (1-lam[k])*sum_c codes[e][c]*codew[c][i][o][k]
// ---------------------------------------------------------------------------
__global__ __launch_bounds__(256) void prep(bf16_t* __restrict__ B1t,
                                            bf16_t* __restrict__ B1,
                                            const float* __restrict__ codes,
                                            const float* __restrict__ comw,
                                            const float* __restrict__ codew,
                                            const float* __restrict__ fw,
                                            float* __restrict__ W) {
  const float C0 = 7.6699039394282061e-4f;         // 2*pi/8192
  if (blockIdx.x < 512) {
    const int id = blockIdx.x * 256 + threadIdx.x;   // 131072 threads
    if (id < 65536) {
      const int l8 = id & 1023, k = id >> 10;        // k in [0,64)
      const int l0 = l8 * 8;
      bf16x8 vc, vs;
#pragma unroll
      for (int j = 0; j < 8; ++j) {
        int r = ((l0 + j) * k) & (L_LEN - 1);
        float s, c;
        __sincosf((float)r * C0, &s, &c);
        vc[j] = (bf16_t)c;
        vs[j] = (bf16_t)(-s);
      }
      *(bf16x8*)(B1t + (size_t)k * L_LEN + l0)           = vc;
      *(bf16x8*)(B1t + (size_t)(MODES + k) * L_LEN + l0) = vs;
    } else {
      const int id2 = id - 65536;
      const int k8 = id2 & 7, l = id2 >> 3;          // l in [0,8192)
      const int kk = k8 * 8;
      bf16x8 vc, vs;
#pragma unroll
      for (int j = 0; j < 8; ++j) {
        int r = (l * (kk + j)) & (L_LEN - 1);
        float s, c;
        __sincosf((float)r * C0, &s, &c);
        vc[j] = (bf16_t)c;
        vs[j] = (bf16_t)(-s);
      }
      *(bf16x8*)(B1 + (size_t)l * NCOMP + kk)         = vc;
      *(bf16x8*)(B1 + (size_t)l * NCOMP + MODES + kk) = vs;
    }
  } else {
    // wmix: thread = (e,i,o,kp), k = 2*kp,2*kp+1 — float4 path end-to-end.
    int id = (blockIdx.x - 512) * 256 + threadIdx.x;   // 262144 threads
    int kp = id & 31;
    int o = (id >> 5) & 31;
    int i = (id >> 10) & 31;
    int e = id >> 15;
    float lam0 = fminf(fmaxf(fw[2 * kp]     * (1.0f / 6.0f) + 0.5f, 0.0f), 1.0f);
    float lam1 = fminf(fmaxf(fw[2 * kp + 1] * (1.0f / 6.0f) + 0.5f, 0.0f), 1.0f);
    f32x4 a = (f32x4){0.f, 0.f, 0.f, 0.f};
#pragma unroll
    for (int c = 0; c < 16; ++c) {
      float cd = codes[e * 16 + c];
      f32x4 p = *(const f32x4*)(codew + ((((c * 32 + i) * 32 + o) * 64) << 1) + kp * 4);
      a += cd * p;
    }
    f32x4 q = *(const f32x4*)(comw + (((i * 32 + o) * 64) << 1) + kp * 4);
    f32x4 r;
    r[0] = lam0 * q[0] + (1.f - lam0) * a[0];
    r[1] = lam0 * q[1] + (1.f - lam0) * a[1];
    r[2] = lam1 * q[2] + (1.f - lam1) * a[2];
    r[3] = lam1 * q[3] + (1.f - lam1) * a[3];
    *(f32x4*)(W + ((((e * 32 + i) * 32 + o) * 64) << 1) + kp * 4) = r;
  }
}

// ---------------------------------------------------------------------------
// Stage 1 (DEPTH-2 counted-vmcnt pipeline, fp16 partials):
// Xp[sp][4096][128] = x[m-tile][k-chunk] * B1t^T, k-chunk = 1024.
// grid = (64 m-tiles, 8 k-splits) = 512 blocks -> 2 blocks/CU, all resident.
// B sub-tile [128][64] TRIPLE-buffered LDS (48 KiB) via g2lds + XOR swizzle.
// A: TWO float4x4 prefetch sets (depth 2). Per iter ch: issue group ch+2
// (4 g2lds + 4 A loads = 8 vmem), then vmcnt(16) = wait group ch only —
// TWO full iteration-groups (64 KB/block) stay in flight across the barriers,
// doubling in-flight bytes vs the depth-1 version (the ~1-2 TB/s limiter).
// mfma(Bfrag, Afrag): C col = m (lane&15), row = n-within-16 (lq*4+rg)
//   -> lane's 4 acc regs are 4 consecutive n -> one 8B f16x4 store.
// ---------------------------------------------------------------------------
__global__ __launch_bounds__(256, 2) void stage1(const float* __restrict__ x,
                                                 const bf16_t* __restrict__ B1t,
                                                 _Float16* __restrict__ Xp) {
  __shared__ bf16_t Bs[3][128 * 64];   // 3 x 16 KiB, swizzled
  const int t = threadIdx.x;
  const int lane = t & 63;
  const int w = t >> 6;
  const int l15 = lane & 15, lq = lane >> 4;
  const int m0 = blockIdx.x * 64 + w * 16;
  const int k0 = blockIdx.y * 1024;

  const float* aptr = x + (size_t)(m0 + l15) * L_LEN + k0 + lq * 8;

#define STAGE_B(CH)                                                            \
  {                                                                            \
    _Pragma("unroll")                                                          \
    for (int q = 0; q < 4; ++q) {                                              \
      int slot = t + 256 * q;                                                  \
      int n = slot >> 3, m8 = slot & 7, j8 = m8 ^ (n & 7);                     \
      g2lds16(B1t + (size_t)n * L_LEN + k0 + (CH) * 64 + j8 * 8,               \
              (char*)(&Bs[(CH) % 3][0]) + slot * 16);                          \
    }                                                                          \
  }
#define LOAD_A(CH, SET)                                                        \
  {                                                                            \
    const float* ap_ = aptr + (CH) * 64;                                       \
    pa[SET][0] = *(const float4*)(ap_ + 0);                                    \
    pa[SET][1] = *(const float4*)(ap_ + 4);                                    \
    pa[SET][2] = *(const float4*)(ap_ + 32);                                   \
    pa[SET][3] = *(const float4*)(ap_ + 36);                                   \
  }

  float4 pa[2][4];
  f32x4 acc[8];
#pragma unroll
  for (int nf = 0; nf < 8; ++nf) acc[nf] = (f32x4){0.f, 0.f, 0.f, 0.f};

  // prologue: groups 0 and 1 in flight (16 vmem)
  STAGE_B(0); LOAD_A(0, 0);
  STAGE_B(1); LOAD_A(1, 1);

#pragma unroll
  for (int ch = 0; ch < NCH; ++ch) {
    // SSA copies of this iteration's A prefetch (set freed for ch+2 below)
    float4 a0 = pa[ch & 1][0], a1 = pa[ch & 1][1],
           a2 = pa[ch & 1][2], a3 = pa[ch & 1][3];
    if (ch < NCH - 2) {
      STAGE_B(ch + 2);
      LOAD_A(ch + 2, ch & 1);
      // outstanding = groups {ch,ch+1,ch+2} = 24; wait until 16 left -> group ch done
      asm volatile("s_waitcnt vmcnt(16)" ::: "memory");
    } else if (ch == NCH - 2) {
      asm volatile("s_waitcnt vmcnt(8)" ::: "memory");
    } else {
      asm volatile("s_waitcnt vmcnt(0)" ::: "memory");
    }
    __builtin_amdgcn_s_barrier();          // all waves' stage(ch) visible
    asm volatile("" ::: "memory");         // keep LDS reads below the barrier
    bf16x8 av0 = {(bf16_t)a0.x, (bf16_t)a0.y, (bf16_t)a0.z, (bf16_t)a0.w,
                  (bf16_t)a1.x, (bf16_t)a1.y, (bf16_t)a1.z, (bf16_t)a1.w};
    bf16x8 av1 = {(bf16_t)a2.x, (bf16_t)a2.y, (bf16_t)a2.z, (bf16_t)a2.w,
                  (bf16_t)a3.x, (bf16_t)a3.y, (bf16_t)a3.z, (bf16_t)a3.w};
    const bf16_t* bb = &Bs[ch % 3][0];
    __builtin_amdgcn_s_setprio(1);
#pragma unroll
    for (int s = 0; s < 2; ++s) {
      bf16x8 av = s ? av1 : av0;
#pragma unroll
      for (int nf = 0; nf < 8; ++nf) {
        int n = nf * 16 + l15;
        int j8 = (s * 4 + lq) ^ (n & 7);
        bf16x8 bv = *(const bf16x8*)(bb + n * 64 + j8 * 8);
        // swapped: A-operand = B1t frag (n rows), B-operand = x frag (m cols)
        acc[nf] = __builtin_amdgcn_mfma_f32_16x16x32_bf16(bv, av, acc[nf], 0, 0, 0);
      }
    }
    __builtin_amdgcn_s_setprio(0);
    // WAR: buf (ch+2)%3 == buf (ch-1)%3 is re-staged at iter ch+... ensure
    // all waves finished reading the buffer staged 3 iterations ago.
    if (ch < NCH - 1) __builtin_amdgcn_s_barrier();
  }
#undef STAGE_B
#undef LOAD_A

  // C layout (swapped): col = lane&15 -> m, row = lq*4+rg -> n-within-16.
  _Float16* xout = Xp + (size_t)blockIdx.y * (M_ROWS * NCOMP) +
                   (size_t)(m0 + l15) * NCOMP + lq * 4;
#pragma unroll
  for (int nf = 0; nf < 8; ++nf)
    *(f16x4*)(xout + nf * 16) = (f16x4){(_Float16)acc[nf][0], (_Float16)acc[nf][1],
                                        (_Float16)acc[nf][2], (_Float16)acc[nf][3]};
}

// ---------------------------------------------------------------------------
// Mix: grid (128 be-blocks, 2 K-HALVES) — k-split so the 8-way Xp reduction
// is not duplicated. Block (be, kh) reduces fp16 Xp cols {kh*32..+32,
// 64+kh*32..+32} into fp32 Xs[32][64], then Y[b,e,o,k] = sum_i X*W for its
// k-window, scaled for irfft, emitted as bf16 A2[m=(b,e,o)][Re k | Im k].
// ---------------------------------------------------------------------------
__global__ __launch_bounds__(256) void mixk(const _Float16* __restrict__ Xp,
                                            const float* __restrict__ W,
                                            bf16_t* __restrict__ A2) {
  __shared__ __align__(16) float Xs[32 * 64];   // [i][Re 0..31 | Im 32..63]
  const int t = threadIdx.x;
  const int be = blockIdx.x;       // b*8+e
  const int kh = blockIdx.y;       // k-half
  const int e = be & 7;
  const int cb = kh * 32;
  const _Float16* xb = Xp + (size_t)be * (32 * NCOMP);
#pragma unroll
  for (int j = 0; j < 2; ++j) {
    int qid = t + 256 * j;               // 512 quads: 32 rows x 16 quads
    int row = qid >> 4, sub = qid & 15;
    int col  = (sub < 8) ? (cb + sub * 4) : (64 + cb + (sub - 8) * 4);
    int scol = (sub < 8) ? (sub * 4)      : (32 + (sub - 8) * 4);
    f32x4 s = (f32x4){0.f, 0.f, 0.f, 0.f};
#pragma unroll
    for (int sp = 0; sp < SPLITS; ++sp) {
      f16x4 v = *(const f16x4*)(xb + (size_t)sp * (M_ROWS * NCOMP) + row * NCOMP + col);
      s[0] += (float)v[0]; s[1] += (float)v[1]; s[2] += (float)v[2]; s[3] += (float)v[3];
    }
    *(f32x4*)(Xs + row * 64 + scol) = s;
  }
  __syncthreads();
  const int kb = t & 31;           // k within half
  const int k = cb + kb;
  const int grp = t >> 5;          // o = grp*4 + j
  float yre[4], yim[4];
#pragma unroll
  for (int j = 0; j < 4; ++j) { yre[j] = 0.f; yim[j] = 0.f; }
  for (int i = 0; i < 32; ++i) {
    float xr = Xs[i * 64 + kb];
    float xi = Xs[i * 64 + 32 + kb];
    const float* wp = W + ((((e * 32 + i) * 32 + grp * 4) * 64 + k) << 1);
#pragma unroll
    for (int j = 0; j < 4; ++j) {
      float2 wv = *(const float2*)(wp + j * 128);
      yre[j] += xr * wv.x - xi * wv.y;
      yim[j] += xr * wv.y + xi * wv.x;
    }
  }
  float sc = (k == 0) ? (1.0f / 8192.0f) : (2.0f / 8192.0f);  // irfft: DC 1/L, others 2/L
#pragma unroll
  for (int j = 0; j < 4; ++j) {
    int m = be * 32 + grp * 4 + j;
    A2[m * NCOMP + k]         = (bf16_t)(yre[j] * sc);
    A2[m * NCOMP + MODES + k] = (bf16_t)(yim[j] * sc);
  }
}

// ---------------------------------------------------------------------------
// Stage 2 (hybrid, SWAPPED mfma operands for x4 stores):
// out[4096][8192] = A2[4096][128] * B1^T (K=128, one shot).
// grid = (64 m-tiles, 64 l-tiles), 4 waves/block; wave: 16 m x 128 l.
// B1 tile (shared x4 waves) staged to LDS (32 KiB); A2 frags direct
// global->reg issued BEFORE the barrier so they ride the staging wait.
// mfma(B1frag, A2frag): C col = m (lane&15), row = l-within-16 (lq*4+rg)
//   -> lane's 4 acc regs are 4 consecutive l -> one float4 store per frag.
// ---------------------------------------------------------------------------
__global__ __launch_bounds__(256) void stage2(const bf16_t* __restrict__ A2,
                                              const bf16_t* __restrict__ B1,
                                              float* __restrict__ out) {
  __shared__ bf16_t Bs[128 * 128];   // 32 KiB, swizzled (16 slots/row)
  const int t = threadIdx.x;
  const int lane = t & 63;
  const int w = t >> 6;
  const int l15 = lane & 15, lq = lane >> 4;
  const int m0 = blockIdx.x * 64 + w * 16;
  const int l0 = blockIdx.y * 128;

#pragma unroll
  for (int q = 0; q < 8; ++q) {
    int slot = t + 256 * q;
    int lr = slot >> 4, m16 = slot & 15, j8 = m16 ^ (lr & 15);
    g2lds16(B1 + (size_t)(l0 + lr) * NCOMP + j8 * 8, (char*)Bs + slot * 16);
  }
  const bf16_t* ap = A2 + (size_t)(m0 + l15) * NCOMP + lq * 8;
  bf16x8 av[4];
#pragma unroll
  for (int s = 0; s < 4; ++s) av[s] = *(const bf16x8*)(ap + s * 32);

  f32x4 acc[8];
#pragma unroll
  for (int nf = 0; nf < 8; ++nf) acc[nf] = (f32x4){0.f, 0.f, 0.f, 0.f};

  __syncthreads();

  __builtin_amdgcn_s_setprio(1);
#pragma unroll
  for (int s = 0; s < 4; ++s) {
#pragma unroll
    for (int nf = 0; nf < 8; ++nf) {
      int lr = nf * 16 + l15;
      int j8 = (s * 4 + lq) ^ (lr & 15);
      bf16x8 bv = *(const bf16x8*)(Bs + lr * 128 + j8 * 8);
      // swapped: A-operand = B1 frag (l rows), B-operand = A2 frag (m cols)
      acc[nf] = __builtin_amdgcn_mfma_f32_16x16x32_bf16(bv, av[s], acc[nf], 0, 0, 0);
    }
  }
  __builtin_amdgcn_s_setprio(0);

  // C layout (swapped): col = lane&15 -> m, row = lq*4+rg -> l-within-16.
  float* op = out + (size_t)(m0 + l15) * L_LEN + l0 + lq * 4;
#pragma unroll
  for (int nf = 0; nf < 8; ++nf)
    *(float4*)(op + nf * 16) = (float4){acc[nf][0], acc[nf][1], acc[nf][2], acc[nf][3]};
}

// ---------------------------------------------------------------------------
// ws layout:  [0,2M)   B1t bf16 [128][8192]
//             [2M,4M)  B1  bf16 [8192][128]
//             [4M,20M) W   fp32 [8][32][32][64][2]
//             [20M,21M) A2 bf16 [4096][128]
//             [24M,33M) Xp fp16 [8][4096][128]   (stage1 split-K partials)
// ---------------------------------------------------------------------------
extern "C" void kernel_launch(void* const* d_in, const int* in_sizes, int n_in,
                              void* d_out, int out_size, void* d_ws, size_t ws_size,
                              hipStream_t stream) {
  const float* x     = (const float*)d_in[0];
  const float* codes = (const float*)d_in[1];
  const float* comw  = (const float*)d_in[2];
  const float* codew = (const float*)d_in[3];
  const float* fw    = (const float*)d_in[4];
  float* out = (float*)d_out;
  char* ws = (char*)d_ws;
  bf16_t*   B1t = (bf16_t*)(ws);
  bf16_t*   B1  = (bf16_t*)(ws + (size_t)(2u << 20));
  float*    W   = (float*) (ws + (size_t)(4u << 20));
  bf16_t*   A2  = (bf16_t*)(ws + (size_t)(20u << 20));
  _Float16* Xp  = (_Float16*)(ws + (size_t)(24u << 20));

  prep<<<1536, 256, 0, stream>>>(B1t, B1, codes, comw, codew, fw, W);
  stage1<<<dim3(64, SPLITS), 256, 0, stream>>>(x, B1t, Xp);
  mixk<<<dim3(128, 2), 256, 0, stream>>>(Xp, W, A2);
  stage2<<<dim3(64, 64), 256, 0, stream>>>(A2, B1, out);
}

// Round 9
// 289.153 us; speedup vs baseline: 1.0350x; 1.0350x over previous
//
#include <hip/hip_runtime.h>
#include <hip/hip_bf16.h>
#include <math.h>
#include <stdint.h>

typedef __bf16 bf16_t;
typedef __bf16 bf16x8 __attribute__((ext_vector_type(8)));
typedef float  f32x4  __attribute__((ext_vector_type(4)));
typedef _Float16 f16x4 __attribute__((ext_vector_type(4)));

#define L_LEN 8192
#define MODES 64
#define NCOMP 128      // 2*MODES (Re | Im)
#define M_ROWS 4096    // B * n_env * ch
#define SPLITS 16      // K-splits in stage1 (k-chunk 512 per block)

// async global->LDS, 16B per lane. LDS dst must be wave-uniform base + lane*16.
__device__ __forceinline__ void g2lds16(const void* g, void* l) {
  __builtin_amdgcn_global_load_lds(
      (__attribute__((address_space(1))) void*)(uintptr_t)(g),
      (__attribute__((address_space(3))) void*)(l), 16, 0, 0);
}

// ---------------------------------------------------------------------------
// prep = gen_basis (blocks [0,512)) + wmix (blocks [512,1536), 2 k per thread).
// Trig: __sincosf (native v_sin/v_cos) — bf16 output tolerates few-ulp error.
// B1t[n][l]  n<64: cos(2*pi*n*l/L)   n>=64: -sin(2*pi*(n-64)*l/L)   [128][8192]
// B1 [l][n]  same values transposed                                  [8192][128]
// W[e][i][o][k] (cplx f32) = lam[k]*cw[i][o][k] + (1-lam[k])*sum_c codes[e][c]*codew[c][i][o][k]
// ---------------------------------------------------------------------------
__global__ __launch_bounds__(256) void prep(bf16_t* __restrict__ B1t,
                                            bf16_t* __restrict__ B1,
                                            const float* __restrict__ codes,
                                            const float* __restrict__ comw,
                                            const float* __restrict__ codew,
                                            const float* __restrict__ fw,
                                            float* __restrict__ W) {
  const float C0 = 7.6699039394282061e-4f;         // 2*pi/8192
  if (blockIdx.x < 512) {
    const int id = blockIdx.x * 256 + threadIdx.x;   // 131072 threads
    if (id < 65536) {
      const int l8 = id & 1023, k = id >> 10;        // k in [0,64)
      const int l0 = l8 * 8;
      bf16x8 vc, vs;
#pragma unroll
      for (int j = 0; j < 8; ++j) {
        int r = ((l0 + j) * k) & (L_LEN - 1);
        float s, c;
        __sincosf((float)r * C0, &s, &c);
        vc[j] = (bf16_t)c;
        vs[j] = (bf16_t)(-s);
      }
      *(bf16x8*)(B1t + (size_t)k * L_LEN + l0)           = vc;
      *(bf16x8*)(B1t + (size_t)(MODES + k) * L_LEN + l0) = vs;
    } else {
      const int id2 = id - 65536;
      const int k8 = id2 & 7, l = id2 >> 3;          // l in [0,8192)
      const int kk = k8 * 8;
      bf16x8 vc, vs;
#pragma unroll
      for (int j = 0; j < 8; ++j) {
        int r = (l * (kk + j)) & (L_LEN - 1);
        float s, c;
        __sincosf((float)r * C0, &s, &c);
        vc[j] = (bf16_t)c;
        vs[j] = (bf16_t)(-s);
      }
      *(bf16x8*)(B1 + (size_t)l * NCOMP + kk)         = vc;
      *(bf16x8*)(B1 + (size_t)l * NCOMP + MODES + kk) = vs;
    }
  } else {
    // wmix: thread = (e,i,o,kp), k = 2*kp,2*kp+1 — float4 path end-to-end.
    int id = (blockIdx.x - 512) * 256 + threadIdx.x;   // 262144 threads
    int kp = id & 31;
    int o = (id >> 5) & 31;
    int i = (id >> 10) & 31;
    int e = id >> 15;
    float lam0 = fminf(fmaxf(fw[2 * kp]     * (1.0f / 6.0f) + 0.5f, 0.0f), 1.0f);
    float lam1 = fminf(fmaxf(fw[2 * kp + 1] * (1.0f / 6.0f) + 0.5f, 0.0f), 1.0f);
    f32x4 a = (f32x4){0.f, 0.f, 0.f, 0.f};
#pragma unroll
    for (int c = 0; c < 16; ++c) {
      float cd = codes[e * 16 + c];
      f32x4 p = *(const f32x4*)(codew + ((((c * 32 + i) * 32 + o) * 64) << 1) + kp * 4);
      a += cd * p;
    }
    f32x4 q = *(const f32x4*)(comw + (((i * 32 + o) * 64) << 1) + kp * 4);
    f32x4 r;
    r[0] = lam0 * q[0] + (1.f - lam0) * a[0];
    r[1] = lam0 * q[1] + (1.f - lam0) * a[1];
    r[2] = lam1 * q[2] + (1.f - lam1) * a[2];
    r[3] = lam1 * q[3] + (1.f - lam1) * a[3];
    *(f32x4*)(W + ((((e * 32 + i) * 32 + o) * 64) << 1) + kp * 4) = r;
  }
}

// ---------------------------------------------------------------------------
// Stage 1 (counted-vmcnt pipeline, SWAPPED mfma operands, fp16 partials):
// Xp[sp][4096][128] (_Float16) = x[m-tile][k-chunk] * B1t^T.
// grid = (64 m-tiles, 16 k-splits), 4 waves/block, wave = 16 rows x 128 comps.
// B tile [128][64] double-buffered LDS via global_load_lds + XOR swizzle.
// mfma(Bfrag, Afrag): C col = m (lane&15), row = n-within-16 (lq*4+rg)
//   -> lane's 4 acc regs are 4 CONSECUTIVE n -> one 8B f16x4 store.
// fp16 partials: |p| <~200 << 65504; adds ~3e-4 rel error on X, ~1e-5 on out.
// Pipeline per iter: issue stage(ch+1)+A(ch+1) [8 vmem]; vmcnt(8) waits only
// iter-ch ops; raw s_barrier (loads stay in flight); MFMA (setprio 1); WAR barrier.
// ---------------------------------------------------------------------------
__global__ __launch_bounds__(256, 4) void stage1(const float* __restrict__ x,
                                                 const bf16_t* __restrict__ B1t,
                                                 _Float16* __restrict__ Xp) {
  __shared__ bf16_t Bs[2][128 * 64];   // 2 x 16 KiB, swizzled
  const int t = threadIdx.x;
  const int lane = t & 63;
  const int w = t >> 6;
  const int l15 = lane & 15, lq = lane >> 4;
  const int m0 = blockIdx.x * 64 + w * 16;
  const int k0 = blockIdx.y * 512;

  const float* aptr = x + (size_t)(m0 + l15) * L_LEN + k0 + lq * 8;

  // prologue: stage chunk 0 into buf 0 (4 g2lds), prefetch A chunk 0 (4 loads)
#pragma unroll
  for (int q = 0; q < 4; ++q) {
    int slot = t + 256 * q;
    int n = slot >> 3, m8 = slot & 7, j8 = m8 ^ (n & 7);
    g2lds16(B1t + (size_t)n * L_LEN + k0 + j8 * 8, (char*)(&Bs[0][0]) + slot * 16);
  }
  float4 pa0 = *(const float4*)(aptr + 0);
  float4 pa1 = *(const float4*)(aptr + 4);
  float4 pa2 = *(const float4*)(aptr + 32);
  float4 pa3 = *(const float4*)(aptr + 36);

  f32x4 acc[8];
#pragma unroll
  for (int nf = 0; nf < 8; ++nf) acc[nf] = (f32x4){0.f, 0.f, 0.f, 0.f};

#pragma unroll
  for (int ch = 0; ch < 8; ++ch) {
    float4 a0 = pa0, a1 = pa1, a2 = pa2, a3 = pa3;
    if (ch < 7) {
#pragma unroll
      for (int q = 0; q < 4; ++q) {
        int slot = t + 256 * q;
        int n = slot >> 3, m8 = slot & 7, j8 = m8 ^ (n & 7);
        g2lds16(B1t + (size_t)n * L_LEN + k0 + (ch + 1) * 64 + j8 * 8,
                (char*)(&Bs[(ch + 1) & 1][0]) + slot * 16);
      }
      const float* ap2 = aptr + (ch + 1) * 64;
      pa0 = *(const float4*)(ap2 + 0);
      pa1 = *(const float4*)(ap2 + 4);
      pa2 = *(const float4*)(ap2 + 32);
      pa3 = *(const float4*)(ap2 + 36);
      asm volatile("s_waitcnt vmcnt(8)" ::: "memory");
    } else {
      asm volatile("s_waitcnt vmcnt(0)" ::: "memory");
    }
    __builtin_amdgcn_s_barrier();          // all waves' stage(ch) visible
    asm volatile("" ::: "memory");         // keep LDS reads below the barrier
    bf16x8 av0 = {(bf16_t)a0.x, (bf16_t)a0.y, (bf16_t)a0.z, (bf16_t)a0.w,
                  (bf16_t)a1.x, (bf16_t)a1.y, (bf16_t)a1.z, (bf16_t)a1.w};
    bf16x8 av1 = {(bf16_t)a2.x, (bf16_t)a2.y, (bf16_t)a2.z, (bf16_t)a2.w,
                  (bf16_t)a3.x, (bf16_t)a3.y, (bf16_t)a3.z, (bf16_t)a3.w};
    const bf16_t* bb = &Bs[ch & 1][0];
    __builtin_amdgcn_s_setprio(1);
#pragma unroll
    for (int s = 0; s < 2; ++s) {
      bf16x8 av = s ? av1 : av0;
#pragma unroll
      for (int nf = 0; nf < 8; ++nf) {
        int n = nf * 16 + l15;
        int j8 = (s * 4 + lq) ^ (n & 7);
        bf16x8 bv = *(const bf16x8*)(bb + n * 64 + j8 * 8);
        // swapped: A-operand = B1t frag (n rows), B-operand = x frag (m cols)
        acc[nf] = __builtin_amdgcn_mfma_f32_16x16x32_bf16(bv, av, acc[nf], 0, 0, 0);
      }
    }
    __builtin_amdgcn_s_setprio(0);
    if (ch < 7) __builtin_amdgcn_s_barrier();   // WAR before buf reuse
  }

  // C layout (swapped): col = lane&15 -> m, row = lq*4+rg -> n-within-16.
  _Float16* xout = Xp + (size_t)blockIdx.y * (M_ROWS * NCOMP) +
                   (size_t)(m0 + l15) * NCOMP + lq * 4;
#pragma unroll
  for (int nf = 0; nf < 8; ++nf)
    *(f16x4*)(xout + nf * 16) = (f16x4){(_Float16)acc[nf][0], (_Float16)acc[nf][1],
                                        (_Float16)acc[nf][2], (_Float16)acc[nf][3]};
}

// ---------------------------------------------------------------------------
// Mix: grid (128 be-blocks, 2 K-HALVES) — k-split so the 16-way Xp reduction
// is not duplicated. Block (be, kh) reduces fp16 Xp cols {kh*32..+32,
// 64+kh*32..+32} into fp32 Xs[32][64], then Y[b,e,o,k] = sum_i X*W for its
// k-window, scaled for irfft, emitted as bf16 A2[m=(b,e,o)][Re k | Im k].
// ---------------------------------------------------------------------------
__global__ __launch_bounds__(256) void mixk(const _Float16* __restrict__ Xp,
                                            const float* __restrict__ W,
                                            bf16_t* __restrict__ A2) {
  __shared__ __align__(16) float Xs[32 * 64];   // [i][Re 0..31 | Im 32..63]
  const int t = threadIdx.x;
  const int be = blockIdx.x;       // b*8+e
  const int kh = blockIdx.y;       // k-half
  const int e = be & 7;
  const int cb = kh * 32;
  const _Float16* xb = Xp + (size_t)be * (32 * NCOMP);
#pragma unroll
  for (int j = 0; j < 2; ++j) {
    int qid = t + 256 * j;               // 512 quads: 32 rows x 16 quads
    int row = qid >> 4, sub = qid & 15;
    int col  = (sub < 8) ? (cb + sub * 4) : (64 + cb + (sub - 8) * 4);
    int scol = (sub < 8) ? (sub * 4)      : (32 + (sub - 8) * 4);
    f32x4 s = (f32x4){0.f, 0.f, 0.f, 0.f};
#pragma unroll
    for (int sp = 0; sp < SPLITS; ++sp) {
      f16x4 v = *(const f16x4*)(xb + (size_t)sp * (M_ROWS * NCOMP) + row * NCOMP + col);
      s[0] += (float)v[0]; s[1] += (float)v[1]; s[2] += (float)v[2]; s[3] += (float)v[3];
    }
    *(f32x4*)(Xs + row * 64 + scol) = s;
  }
  __syncthreads();
  const int kb = t & 31;           // k within half
  const int k = cb + kb;
  const int grp = t >> 5;          // o = grp*4 + j
  float yre[4], yim[4];
#pragma unroll
  for (int j = 0; j < 4; ++j) { yre[j] = 0.f; yim[j] = 0.f; }
  for (int i = 0; i < 32; ++i) {
    float xr = Xs[i * 64 + kb];
    float xi = Xs[i * 64 + 32 + kb];
    const float* wp = W + ((((e * 32 + i) * 32 + grp * 4) * 64 + k) << 1);
#pragma unroll
    for (int j = 0; j < 4; ++j) {
      float2 wv = *(const float2*)(wp + j * 128);
      yre[j] += xr * wv.x - xi * wv.y;
      yim[j] += xr * wv.y + xi * wv.x;
    }
  }
  float sc = (k == 0) ? (1.0f / 8192.0f) : (2.0f / 8192.0f);  // irfft: DC 1/L, others 2/L
#pragma unroll
  for (int j = 0; j < 4; ++j) {
    int m = be * 32 + grp * 4 + j;
    A2[m * NCOMP + k]         = (bf16_t)(yre[j] * sc);
    A2[m * NCOMP + MODES + k] = (bf16_t)(yim[j] * sc);
  }
}

// ---------------------------------------------------------------------------
// Stage 2 (hybrid, SWAPPED mfma operands for x4 stores):
// out[4096][8192] = A2[4096][128] * B1^T (K=128, one shot).
// grid = (64 m-tiles, 64 l-tiles), 4 waves/block; wave: 16 m x 128 l.
// B1 tile (shared x4 waves) staged to LDS (32 KiB); A2 frags direct
// global->reg issued BEFORE the barrier so they ride the staging wait.
// mfma(B1frag, A2frag): C col = m (lane&15), row = l-within-16 (lq*4+rg)
//   -> lane's 4 acc regs are 4 consecutive l -> one float4 store per frag.
// ---------------------------------------------------------------------------
__global__ __launch_bounds__(256) void stage2(const bf16_t* __restrict__ A2,
                                              const bf16_t* __restrict__ B1,
                                              float* __restrict__ out) {
  __shared__ bf16_t Bs[128 * 128];   // 32 KiB, swizzled (16 slots/row)
  const int t = threadIdx.x;
  const int lane = t & 63;
  const int w = t >> 6;
  const int l15 = lane & 15, lq = lane >> 4;
  const int m0 = blockIdx.x * 64 + w * 16;
  const int l0 = blockIdx.y * 128;

#pragma unroll
  for (int q = 0; q < 8; ++q) {
    int slot = t + 256 * q;
    int lr = slot >> 4, m16 = slot & 15, j8 = m16 ^ (lr & 15);
    g2lds16(B1 + (size_t)(l0 + lr) * NCOMP + j8 * 8, (char*)Bs + slot * 16);
  }
  const bf16_t* ap = A2 + (size_t)(m0 + l15) * NCOMP + lq * 8;
  bf16x8 av[4];
#pragma unroll
  for (int s = 0; s < 4; ++s) av[s] = *(const bf16x8*)(ap + s * 32);

  f32x4 acc[8];
#pragma unroll
  for (int nf = 0; nf < 8; ++nf) acc[nf] = (f32x4){0.f, 0.f, 0.f, 0.f};

  __syncthreads();

  __builtin_amdgcn_s_setprio(1);
#pragma unroll
  for (int s = 0; s < 4; ++s) {
#pragma unroll
    for (int nf = 0; nf < 8; ++nf) {
      int lr = nf * 16 + l15;
      int j8 = (s * 4 + lq) ^ (lr & 15);
      bf16x8 bv = *(const bf16x8*)(Bs + lr * 128 + j8 * 8);
      // swapped: A-operand = B1 frag (l rows), B-operand = A2 frag (m cols)
      acc[nf] = __builtin_amdgcn_mfma_f32_16x16x32_bf16(bv, av[s], acc[nf], 0, 0, 0);
    }
  }
  __builtin_amdgcn_s_setprio(0);

  // C layout (swapped): col = lane&15 -> m, row = lq*4+rg -> l-within-16.
  float* op = out + (size_t)(m0 + l15) * L_LEN + l0 + lq * 4;
#pragma unroll
  for (int nf = 0; nf < 8; ++nf)
    *(float4*)(op + nf * 16) = (float4){acc[nf][0], acc[nf][1], acc[nf][2], acc[nf][3]};
}

// ---------------------------------------------------------------------------
// ws layout:  [0,2M)   B1t bf16 [128][8192]
//             [2M,4M)  B1  bf16 [8192][128]
//             [4M,20M) W   fp32 [8][32][32][64][2]
//             [20M,21M) A2 bf16 [4096][128]
//             [24M,41M) Xp fp16 [16][4096][128]   (stage1 split-K partials)
// ---------------------------------------------------------------------------
extern "C" void kernel_launch(void* const* d_in, const int* in_sizes, int n_in,
                              void* d_out, int out_size, void* d_ws, size_t ws_size,
                              hipStream_t stream) {
  const float* x     = (const float*)d_in[0];
  const float* codes = (const float*)d_in[1];
  const float* comw  = (const float*)d_in[2];
  const float* codew = (const float*)d_in[3];
  const float* fw    = (const float*)d_in[4];
  float* out = (float*)d_out;
  char* ws = (char*)d_ws;
  bf16_t*   B1t = (bf16_t*)(ws);
  bf16_t*   B1  = (bf16_t*)(ws + (size_t)(2u << 20));
  float*    W   = (float*) (ws + (size_t)(4u << 20));
  bf16_t*   A2  = (bf16_t*)(ws + (size_t)(20u << 20));
  _Float16* Xp  = (_Float16*)(ws + (size_t)(24u << 20));

  prep<<<1536, 256, 0, stream>>>(B1t, B1, codes, comw, codew, fw, W);
  stage1<<<dim3(64, SPLITS), 256, 0, stream>>>(x, B1t, Xp);
  mixk<<<dim3(128, 2), 256, 0, stream>>>(Xp, W, A2);
  stage2<<<dim3(64, 64), 256, 0, stream>>>(A2, B1, out);
}